// Round 3
// baseline (285.261 us; speedup 1.0000x reference)
//
#include <hip/hip_runtime.h>

// Top2Gating, S=8192 tokens, E=64 experts, capacity=256.
// Output (FLOAT32, flat): [ l_aux (1) | combine_weights (S*E*CAP) | dispatch_mask (S*E*CAP) ]
// (reference outputs are f32/bool -> harness d_out is float*, NOT bf16)
// No d_ws use: intermediates live temporarily inside d_out territories and are
// re-zeroed before the final scatter (ordering via stream kernel boundaries).

namespace {
constexpr int  TOK  = 8192;
constexpr int  NEXP = 64;
constexpr int  CAPC = 256;
constexpr int  CHK  = 128;
constexpr int  NCHK = TOK / CHK;                         // 64
constexpr long long TERR = (long long)CHK * NEXP * CAPC; // 4,194,304 floats / chunk territory
constexpr long long SEC  = (long long)TOK * NEXP * CAPC; // 134,217,728 floats / dense output
constexpr float NEGMIN = -3.402823466e38f;               // finfo(f32).min
constexpr float EPSF   = 1.1920929e-7f;                  // finfo(f32).eps
// raw record @ head of chunk's COMBINE territory (word offsets):
//   int i12[128]@0   f32 g1[128]@128   f32 g2[128]@256
//   int h1[64]@384   int h2[64]@448    f32 me[64]@512      -> 576 words
// package  @ head of chunk's DISPATCH territory:
//   int i12[128]@0   f32 g1[128]@128   f32 g2[128]@256
//   int b1[64]@384   int b2full[64]@448                    -> 512 words
}

__device__ __forceinline__ float wave_max64(float v) {
    for (int o = 32; o; o >>= 1) v = fmaxf(v, __shfl_xor(v, o));
    return v;
}
__device__ __forceinline__ float wave_sum64(float v) {
    for (int o = 32; o; o >>= 1) v += __shfl_xor(v, o);
    return v;
}
__device__ __forceinline__ float* raw_base(float* out, int c) { return out + 1 + (long long)c * TERR; }
__device__ __forceinline__ float* pkg_base(float* out, int c) { return out + 1 + SEC + (long long)c * TERR; }

// ---- Phase 1: per-row softmax + top1/top2 (first-max semantics), per-chunk hist/me.
__global__ __launch_bounds__(256) void tg_gate(const float* __restrict__ logits,
                                               const float* __restrict__ noise,
                                               float* __restrict__ out)
{
    __shared__ int   h1[NEXP], h2[NEXP];
    __shared__ float meSh[256];
    const int tid = threadIdx.x, lane = tid & 63, wv = tid >> 6;
    const int c = blockIdx.x;
    float* raw = raw_base(out, c);

    if (tid < NEXP) { h1[tid] = 0; h2[tid] = 0; }
    __syncthreads();

    float meAcc = 0.f;
    for (int i = 0; i < CHK / 4; ++i) {
        const int rloc = i * 4 + wv;
        const int row  = c * CHK + rloc;
        const float l = logits[row * NEXP + lane];
        const float n = noise [row * NEXP + lane];

        const float m    = wave_max64(l);
        const float ex   = __expf(l - m);
        const float sm   = wave_sum64(ex);
        const float gate = ex / sm;

        const unsigned long long b1 = __ballot(l == m);    // argmax(gates)==argmax(logits)
        const int   i1 = __ffsll(b1) - 1;                  // first max wins (jnp.argmax)
        const float G1 = __shfl(gate, i1);

        const float lw = (lane == i1) ? NEGMIN : (l + n);  // mask winner with finfo.min
        const float m2 = wave_max64(lw);
        const unsigned long long b2 = __ballot(lw == m2);
        const int   i2 = __ffsll(b2) - 1;
        const float G2 = __shfl(gate, i2);

        if (lane == 0) {
            ((int*)raw)[rloc] = i1 | (i2 << 8);
            raw[128 + rloc]   = G1;
            raw[256 + rloc]   = G2;
            atomicAdd(&h1[i1], 1);
            atomicAdd(&h2[i2], 1);
        }
        meAcc += gate;
    }

    meSh[tid] = meAcc;
    __syncthreads();
    if (tid < NEXP) {
        ((int*)raw)[384 + tid] = h1[tid];
        ((int*)raw)[448 + tid] = h2[tid];
        raw[512 + tid] = meSh[tid] + meSh[64 + tid] + meSh[128 + tid] + meSh[192 + tid];
    }
}

// ---- Phase 2: cross-chunk exclusive scan, l_aux, relocate packages, re-zero raw areas.
__global__ __launch_bounds__(256) void tg_prefix(float* __restrict__ out)
{
    __shared__ int b2tmp[NCHK][NEXP];
    const int tid = threadIdx.x;

    if (tid < NEXP) {
        const int e = tid;
        int r1 = 0, r2 = 0;
        float ms = 0.f;
        for (int c = 0; c < NCHK; ++c) {
            float* raw = raw_base(out, c);
            float* pkg = pkg_base(out, c);
            ((int*)pkg)[384 + e] = r1;                 // exclusive base1
            b2tmp[c][e] = r2;
            r1 += ((int*)raw)[384 + e];
            r2 += ((int*)raw)[448 + e];
            ms += raw[512 + e];
        }
        for (int c = 0; c < NCHK; ++c)                 // base2 + tot1 offset
            ((int*)pkg_base(out, c))[448 + e] = b2tmp[c][e] + r1;

        float term = (ms * (1.f / TOK)) * ((float)r1 * (1.f / TOK)) * (float)(NEXP * NEXP);
        term = wave_sum64(term);
        if (e == 0) out[0] = term * (1.f / NEXP);      // l_aux
    }
    __syncthreads();

    // relocate i12/g1/g2 (384 words per chunk) raw -> pkg
    for (int t = tid; t < NCHK * 384; t += 256) {
        const int c = t / 384, w = t % 384;
        ((int*)pkg_base(out, c))[w] = ((int*)raw_base(out, c))[w];
    }
    __syncthreads();

    // re-zero raw areas (576 words at the head of each combine territory)
    for (int t = tid; t < NCHK * 576; t += 256) {
        const int c = t / 576, w = t % 576;
        raw_base(out, c)[w] = 0.f;
    }
}

// ---- Phase 3: per-chunk ordered replay, capacity masking, renorm, scatter.
__global__ __launch_bounds__(64) void tg_scatter(float* __restrict__ out)
{
    const int e = threadIdx.x, c = blockIdx.x;
    float* pkg = pkg_base(out, c);
    const int   i12a = ((int*)pkg)[e],   i12b = ((int*)pkg)[64 + e];
    const float G1a  = pkg[128 + e],     G1b  = pkg[192 + e];
    const float G2a  = pkg[256 + e],     G2b  = pkg[320 + e];
    int cnt1 = ((int*)pkg)[384 + e];
    int cnt2 = ((int*)pkg)[448 + e];                   // already includes +tot1
    __syncthreads();

    // zero own package area (512 words) before final writes
    for (int w = e; w < 512; w += 64) pkg[w] = 0.f;
    __syncthreads();

    float* comb = out + 1;
    float* disp = out + 1 + SEC;
    const int b = c * CHK;

    for (int s = 0; s < CHK; ++s) {
        const int src = s & 63;
        const int   i12 = __shfl((s < 64) ? i12a : i12b, src);
        const float G1  = __shfl((s < 64) ? G1a  : G1b,  src);
        const float G2  = __shfl((s < 64) ? G2a  : G2b,  src);
        const int i1 = i12 & 255, i2 = i12 >> 8;

        const int loc1 = __shfl(cnt1, i1);
        const int loc2 = __shfl(cnt2, i2);
        cnt1 += (e == i1);
        cnt2 += (e == i2);

        const bool k1 = loc1 < CAPC, k2 = loc2 < CAPC;
        const float ge1 = k1 ? G1 : 0.f;
        const float ge2 = k2 ? G2 : 0.f;
        const float dn  = fmaxf(ge1 + ge2, EPSF);      // post-drop renormalization

        const long long ro = ((long long)(b + s) * NEXP + e) * CAPC;
        if (e == i1 && k1) { comb[ro + loc1] = ge1 / dn; disp[ro + loc1] = 1.f; }
        if (e == i2 && k2) { comb[ro + loc2] = ge2 / dn; disp[ro + loc2] = 1.f; }
    }
}

extern "C" void kernel_launch(void* const* d_in, const int* in_sizes, int n_in,
                              void* d_out, int out_size, void* d_ws, size_t ws_size,
                              hipStream_t stream)
{
    (void)d_ws; (void)ws_size; (void)in_sizes; (void)n_in;
    const float* logits = (const float*)d_in[0];
    const float* noise  = (const float*)d_in[1];
    float* out = (float*)d_out;

    // Harness poisons d_out once before timing and never re-poisons: clear every call.
    hipMemsetAsync(d_out, 0, (size_t)out_size * sizeof(float), stream);

    tg_gate   <<<NCHK, 256, 0, stream>>>(logits, noise, out);
    tg_prefix <<<1,    256, 0, stream>>>(out);
    tg_scatter<<<NCHK,  64, 0, stream>>>(out);
}